// Round 2
// baseline (583.888 us; speedup 1.0000x reference)
//
#include <hip/hip_runtime.h>

// Project2Dto3D: out[b,c,v] = sum over pixels hw with proj[hw]==v of feat[b,c,hw]
// B=4, C=128, H=240, W=320, V=60*36*60=129600
//
// Strategy: counting-sort pixels by voxel (CSR), then gather with independent
// (non-chained) feat loads, 8 bc-slices per thread, coalesced output stores.

static constexpr int HW = 240 * 320;      // 76800
static constexpr int V  = 60 * 36 * 60;   // 129600
static constexpr int B  = 4;
static constexpr int C  = 128;
static constexpr int BC = B * C;          // 512
static constexpr int BCPT = 8;            // bc-slices per gather thread

// ---------------------------------------------------------------------------
// Phase 1: zero the per-voxel counts
__global__ void __launch_bounds__(256) zero_kernel(int* __restrict__ cnt) {
    int i = blockIdx.x * 256 + threadIdx.x;
    if (i < V) cnt[i] = 0;
}

// Phase 2: histogram pixels per voxel
__global__ void __launch_bounds__(256) count_kernel(const int* __restrict__ idx,
                                                    int* __restrict__ cnt) {
    int hw = blockIdx.x * 256 + threadIdx.x;
    if (hw < HW) atomicAdd(&cnt[idx[hw]], 1);
}

// Phase 3: single-block exclusive scan over V counts (in place), copy to cursor.
// 1024 threads x chunk of 127 contiguous elements each.
__global__ void __launch_bounds__(1024) scan_kernel(int* __restrict__ cnt,
                                                    int* __restrict__ cursor) {
    __shared__ int partial[1024];
    const int t = threadIdx.x;
    const int CHUNK = (V + 1023) / 1024;          // 127
    const int lo = t * CHUNK;
    const int hi = (lo + CHUNK < V) ? lo + CHUNK : V;

    int s = 0;
    for (int i = lo; i < hi; ++i) s += cnt[i];
    partial[t] = s;
    __syncthreads();

    // Hillis-Steele inclusive scan over the 1024 partials
    for (int d = 1; d < 1024; d <<= 1) {
        int val = (t >= d) ? partial[t - d] : 0;
        __syncthreads();
        if (t >= d) partial[t] += val;
        __syncthreads();
    }

    int base = partial[t] - s;                    // exclusive prefix for this chunk
    for (int i = lo; i < hi; ++i) {
        int c = cnt[i];
        cnt[i] = base;                            // cnt[] becomes exclusive offsets
        cursor[i] = base;
        base += c;
    }
}

// Phase 4: fill the permutation (pixel ids grouped by voxel)
__global__ void __launch_bounds__(256) perm_kernel(const int* __restrict__ idx,
                                                   int* __restrict__ cursor,
                                                   int* __restrict__ perm) {
    int hw = blockIdx.x * 256 + threadIdx.x;
    if (hw < HW) {
        int v = idx[hw];
        int pos = atomicAdd(&cursor[v], 1);
        perm[pos] = hw;
    }
}

// Phase 5: gather. Thread = (voxel v, group of 8 consecutive bc slices).
// All feat loads are independent (no pointer chase); output stores coalesced.
__global__ void __launch_bounds__(256) gather_kernel(const float* __restrict__ feat,
                                                     const int* __restrict__ off,
                                                     const int* __restrict__ perm,
                                                     float* __restrict__ out) {
    int v = blockIdx.x * 256 + threadIdx.x;
    if (v >= V) return;
    int bc0 = blockIdx.y * BCPT;

    int j0 = off[v];
    int j1 = (v == V - 1) ? HW : off[v + 1];

    const float* f = feat + (long long)bc0 * HW;
    float s[BCPT];
#pragma unroll
    for (int k = 0; k < BCPT; ++k) s[k] = 0.f;

    for (int j = j0; j < j1; ++j) {
        int p = perm[j];
#pragma unroll
        for (int k = 0; k < BCPT; ++k) s[k] += f[p + k * HW];
    }

    long long o = (long long)bc0 * V + v;
    // Nontemporal: keep the 265MB output stream from evicting the feat array
    // (random-order re-reads want LLC residency).
#pragma unroll
    for (int k = 0; k < BCPT; ++k)
        __builtin_nontemporal_store(s[k], &out[o + (long long)k * V]);
}

extern "C" void kernel_launch(void* const* d_in, const int* in_sizes, int n_in,
                              void* d_out, int out_size, void* d_ws, size_t ws_size,
                              hipStream_t stream) {
    const float* feat = (const float*)d_in[0];   // [4,128,240,320] f32
    const int*   idx  = (const int*)d_in[1];     // [240,320] int
    float*       out  = (float*)d_out;           // [4,128,129600] f32

    // workspace layout (ints): off[V] | cursor[V] | perm[HW]  (~1.34 MB)
    int* off    = (int*)d_ws;
    int* cursor = off + V;
    int* perm   = cursor + V;

    zero_kernel <<<(V + 255) / 256, 256, 0, stream>>>(off);
    count_kernel<<<(HW + 255) / 256, 256, 0, stream>>>(idx, off);
    scan_kernel <<<1, 1024, 0, stream>>>(off, cursor);
    perm_kernel <<<(HW + 255) / 256, 256, 0, stream>>>(idx, cursor, perm);

    dim3 grid((V + 255) / 256, BC / BCPT);
    gather_kernel<<<grid, 256, 0, stream>>>(feat, off, perm, out);
}

// Round 3
// 198.228 us; speedup vs baseline: 2.9455x; 2.9455x over previous
//
#include <hip/hip_runtime.h>

// Project2Dto3D: out[b,c,v] = sum over pixels hw with proj[hw]==v of feat[b,c,hw]
// B=4, C=128, H=240, W=320, V=60*36*60=129600
//
// CSR build (count -> hierarchical scan -> perm) + XCD-swizzled gather.

static constexpr int HW = 240 * 320;      // 76800
static constexpr int V  = 60 * 36 * 60;   // 129600
static constexpr int B  = 4;
static constexpr int C  = 128;
static constexpr int BC = B * C;          // 512
static constexpr int BCPT = 8;            // bc-slices per gather thread
static constexpr int NG   = BC / BCPT;    // 64 groups
static constexpr int NBV  = (V + 255) / 256;   // 507 voxel-blocks
static constexpr int NXCD = 8;
static constexpr int GPX  = NG / NXCD;    // 8 groups per XCD

// ---------------------------------------------------------------------------
__global__ void __launch_bounds__(256) zero_kernel(int* __restrict__ cnt) {
    int i = blockIdx.x * 256 + threadIdx.x;
    if (i < V) cnt[i] = 0;
}

__global__ void __launch_bounds__(256) count_kernel(const int* __restrict__ idx,
                                                    int* __restrict__ cnt) {
    int hw = blockIdx.x * 256 + threadIdx.x;
    if (hw < HW) atomicAdd(&cnt[idx[hw]], 1);
}

// Scan stage 1: per-block (256-wide) reduction of counts -> bsum[507]
__global__ void __launch_bounds__(256) blocksum_kernel(const int* __restrict__ cnt,
                                                       int* __restrict__ bsum) {
    int i = blockIdx.x * 256 + threadIdx.x;
    int v = (i < V) ? cnt[i] : 0;
#pragma unroll
    for (int d = 32; d > 0; d >>= 1) v += __shfl_down(v, d, 64);
    __shared__ int ws[4];
    if ((threadIdx.x & 63) == 0) ws[threadIdx.x >> 6] = v;
    __syncthreads();
    if (threadIdx.x == 0) bsum[blockIdx.x] = ws[0] + ws[1] + ws[2] + ws[3];
}

// Scan stage 2: single small block scans the 507 block sums (exclusive)
__global__ void __launch_bounds__(512) scan_bsum_kernel(int* __restrict__ bsum) {
    __shared__ int sm[512];
    int t = threadIdx.x;
    int v = (t < NBV) ? bsum[t] : 0;
    sm[t] = v;
    __syncthreads();
    for (int d = 1; d < 512; d <<= 1) {
        int x = (t >= d) ? sm[t - d] : 0;
        __syncthreads();
        sm[t] += x;
        __syncthreads();
    }
    if (t < NBV) bsum[t] = sm[t] - v;   // exclusive
}

// Scan stage 3: in-block exclusive scan + block offset; off aliases cnt (in place).
__global__ void __launch_bounds__(256) scatter_off_kernel(int* __restrict__ cnt,
                                                          const int* __restrict__ bsum,
                                                          int* __restrict__ cursor) {
    int i = blockIdx.x * 256 + threadIdx.x;
    int c = (i < V) ? cnt[i] : 0;
    int lane = threadIdx.x & 63, w = threadIdx.x >> 6;
    int inc = c;
#pragma unroll
    for (int d = 1; d < 64; d <<= 1) {
        int x = __shfl_up(inc, d, 64);
        if (lane >= d) inc += x;
    }
    __shared__ int wsum[4];
    if (lane == 63) wsum[w] = inc;
    __syncthreads();
    int woff = 0;
    for (int k = 0; k < w; ++k) woff += wsum[k];
    int excl = inc - c + woff + bsum[blockIdx.x];
    if (i < V) { cnt[i] = excl; cursor[i] = excl; }
}

// Phase 4: fill permutation (pixels grouped by voxel)
__global__ void __launch_bounds__(256) perm_kernel(const int* __restrict__ idx,
                                                   int* __restrict__ cursor,
                                                   int* __restrict__ perm) {
    int hw = blockIdx.x * 256 + threadIdx.x;
    if (hw < HW) {
        int v = idx[hw];
        int pos = atomicAdd(&cursor[v], 1);
        perm[pos] = hw;
    }
}

// Phase 5: gather, XCD-swizzled. Assuming round-robin dispatch (xcd = bid%8),
// XCD x exclusively owns bc-groups [8x, 8x+8): its 8x2.4MB feat slices are
// fetched once and off/perm stay L2-resident across its 8 passes.
__global__ void __launch_bounds__(256) gather_kernel(const float* __restrict__ feat,
                                                     const int* __restrict__ off,
                                                     const int* __restrict__ perm,
                                                     float* __restrict__ out) {
    int bid  = blockIdx.x;
    int xcd  = bid & (NXCD - 1);
    int lid  = bid >> 3;              // 0 .. 8*507-1
    int gloc = lid / NBV;             // 0..7
    int vblk = lid - gloc * NBV;      // 0..506
    int g    = xcd * GPX + gloc;      // bc-group 0..63
    int v    = vblk * 256 + threadIdx.x;
    if (v >= V) return;
    int bc0 = g * BCPT;

    int j0 = off[v];
    int j1 = (v == V - 1) ? HW : off[v + 1];

    const float* f = feat + (long long)bc0 * HW;
    float s[BCPT];
#pragma unroll
    for (int k = 0; k < BCPT; ++k) s[k] = 0.f;

    for (int j = j0; j < j1; ++j) {
        int p = perm[j];
#pragma unroll
        for (int k = 0; k < BCPT; ++k) s[k] += f[p + k * HW];
    }

    long long o = (long long)bc0 * V + v;
#pragma unroll
    for (int k = 0; k < BCPT; ++k)
        __builtin_nontemporal_store(s[k], &out[o + (long long)k * V]);
}

extern "C" void kernel_launch(void* const* d_in, const int* in_sizes, int n_in,
                              void* d_out, int out_size, void* d_ws, size_t ws_size,
                              hipStream_t stream) {
    const float* feat = (const float*)d_in[0];   // [4,128,240,320] f32
    const int*   idx  = (const int*)d_in[1];     // [240,320] int
    float*       out  = (float*)d_out;           // [4,128,129600] f32

    // workspace (ints): off/cnt[V] | cursor[V] | perm[HW] | bsum[512]  (~1.34 MB)
    int* off    = (int*)d_ws;
    int* cursor = off + V;
    int* perm   = cursor + V;
    int* bsum   = perm + HW;

    zero_kernel       <<<NBV, 256, 0, stream>>>(off);
    count_kernel      <<<(HW + 255) / 256, 256, 0, stream>>>(idx, off);
    blocksum_kernel   <<<NBV, 256, 0, stream>>>(off, bsum);
    scan_bsum_kernel  <<<1, 512, 0, stream>>>(bsum);
    scatter_off_kernel<<<NBV, 256, 0, stream>>>(off, bsum, cursor);
    perm_kernel       <<<(HW + 255) / 256, 256, 0, stream>>>(idx, cursor, perm);

    gather_kernel<<<NXCD * GPX * NBV, 256, 0, stream>>>(feat, off, perm, out);
}